// Round 9
// baseline (164.826 us; speedup 1.0000x reference)
//
#include <hip/hip_runtime.h>

#define B_ 32
#define T_ 2048
#define C_ 64
#define NP_ 2060          // unique p positions per batch: t + 2k, t<2048, k<7
#define MSTRIDE 144       // floats per 12x12 matrix in global ws
#define LSTRIDE 148       // padded LDS stride for k3 staging
#define P2_ 128           // p's per k12 block (2 matrices per thread)
#define DXS 129           // dxT stride: (c*129+pp)%32 distinct across c and pp

#define DXT_FLOATS (64 * DXS)            // 8256
#define ASKC_FLOATS (16 * 144)           // 2304
#define K12_SMEM (DXT_FLOATS + ASKC_FLOATS)  // 10560 floats = 42240 B

// ------------------------------------------------------------------
// Quad-lane DPP broadcast: all 4 lanes of a quad get lane Q's value.
// ------------------------------------------------------------------
template <int Q>
__device__ __forceinline__ float qb(float v) {
  return __int_as_float(
      __builtin_amdgcn_mov_dpp(__float_as_int(v), Q * 0x55, 0xf, 0xf, true));
}

// C(3x12, own rows) = A(3x12) * B(12x12 quad-distributed) ; ACC: c += if true
template <bool ACC>
__device__ __forceinline__ void qmm_t(const float a[3][12], const float b[3][12],
                                      float c[3][12]) {
  if (!ACC) {
#pragma unroll
    for (int i = 0; i < 3; ++i)
#pragma unroll
      for (int j = 0; j < 12; ++j) c[i][j] = 0.f;
  }
#define QMM_K(OWNER, E)                                                  \
  {                                                                      \
    float bk[12];                                                        \
    _Pragma("unroll")                                                    \
    for (int j = 0; j < 12; ++j) bk[j] = qb<OWNER>(b[E][j]);             \
    _Pragma("unroll")                                                    \
    for (int i = 0; i < 3; ++i) {                                        \
      const float av = a[i][3 * OWNER + E];                              \
      _Pragma("unroll")                                                  \
      for (int j = 0; j < 12; ++j) c[i][j] = fmaf(av, bk[j], c[i][j]);   \
    }                                                                    \
  }
  QMM_K(0, 0) QMM_K(0, 1) QMM_K(0, 2)
  QMM_K(1, 0) QMM_K(1, 1) QMM_K(1, 2)
  QMM_K(2, 0) QMM_K(2, 1) QMM_K(2, 2)
  QMM_K(3, 0) QMM_K(3, 1) QMM_K(3, 2)
#undef QMM_K
}
__device__ __forceinline__ void qmm(const float a[3][12], const float b[3][12],
                                    float c[3][12]) { qmm_t<false>(a, b, c); }
__device__ __forceinline__ void qmma(const float a[3][12], const float b[3][12],
                                     float c[3][12]) { qmm_t<true>(a, b, c); }

// ------------------------------------------------------------------
// In-register expm of pre-scaled (2^-5) skew matrix held as 3 rows/lane.
// PS-6 Taylor (3 mults) + 5 squarings = 8 qmm. Exactly 3 arrays live.
// Result returned in a.
// ------------------------------------------------------------------
__device__ __forceinline__ void expm_ps6(float (&a)[3][12], const int r) {
  float t2[3][12], t3[3][12];
  qmm(a, a, t2);      // M2
  qmm(t2, a, t3);     // M3
  // fused overwrite: t2 <- I + M + M2/2 + M3/6 ; a <- W = M/24+M2/120+M3/720
#pragma unroll
  for (int i = 0; i < 3; ++i)
#pragma unroll
    for (int j = 0; j < 12; ++j) {
      const float av = a[i][j], t2v = t2[i][j], t3v = t3[i][j];
      t2[i][j] = av + t2v * 0.5f + t3v * (1.0f / 6.0f) +
                 ((j == 3 * r + i) ? 1.0f : 0.0f);
      a[i][j] = av * (1.0f / 24.0f) + t2v * (1.0f / 120.0f) +
                t3v * (1.0f / 720.0f);
    }
  qmma(t3, a, t2);    // t2 += M3*W  (now t2 = full degree-6 polynomial)
  // 5 squarings, ping-pong; result lands in t3
  qmm(t2, t2, t3);
  qmm(t3, t3, t2);
  qmm(t2, t2, t3);
  qmm(t3, t3, t2);
  qmm(t2, t2, t3);
#pragma unroll
  for (int i = 0; i < 3; ++i)
#pragma unroll
    for (int j = 0; j < 12; ++j) a[i][j] = t3[i][j];
}

// ------------------------------------------------------------------
// K12: build TWO scaled M's per thread (p=p0+nl and p0+64+nl; thread owns
// rows 3eg..3eg+2), then expm both (second parked in LDS during first's
// expm to keep live set at 3 arrays), write E to global.
// dxT[64][129] (33 KB) + askc[16][144] chunk (9 KB): ask reads amortized
// over 2 matrices -> half the LDS issue per output vs round 8.
// ------------------------------------------------------------------
__global__ __launch_bounds__(256) void k12_build_expm(const float* __restrict__ x,
                                                      const float* __restrict__ A,
                                                      float* __restrict__ E) {
  __shared__ float smem[K12_SMEM];
  float* dxT = smem;                     // [64][DXS]
  float* askc = smem + DXT_FLOATS;       // [16][144]
  const int b = blockIdx.y;
  const int p0 = blockIdx.x * P2_;
  const int tid = threadIdx.x;
  const int eg = tid & 3;                // lane in quad: rows 3eg..3eg+2
  const int nl = tid >> 2;               // quad id 0..63

  // ---- stage dxT (coalesced global reads, conflict-free LDS writes) ----
  const float* xb = x + (size_t)b * T_ * C_;
  for (int i = tid; i < P2_ * C_; i += 256) {
    const int pp = i >> 6, c = i & 63;
    const int p = p0 + pp;
    const int i1 = min(max(p - 7, 0), T_ - 1);
    const int i2 = min(max(p - 5, 0), T_ - 1);
    dxT[c * DXS + pp] = xb[(size_t)i2 * C_ + c] - xb[(size_t)i1 * C_ + c];
  }

  // ---- build both matrices over 4 c-chunks ----
  float acc0[3][12], acc1[3][12];
  float* a0 = &acc0[0][0];
  float* a1 = &acc1[0][0];
#pragma unroll
  for (int j = 0; j < 36; ++j) { a0[j] = 0.f; a1[j] = 0.f; }
  const int e0 = eg * 36;
  const float sc = 1.0f / 32.0f;         // 2^-5 expm scaling folded in

  for (int chunk = 0; chunk < 4; ++chunk) {
    __syncthreads();                     // prev reads done / dxT staged
    for (int i = tid; i < ASKC_FLOATS; i += 256) {
      const int cl = i / 144, e = i - cl * 144;
      const int h = e / 12, w = e - h * 12;
      const int c = chunk * 16 + cl;
      askc[cl * 144 + e] = (A[c * 144 + e] - A[c * 144 + w * 12 + h]) * sc;
    }
    __syncthreads();
#pragma unroll
    for (int cc = 0; cc < 16; ++cc) {
      const int c = chunk * 16 + cc;
      const float d0 = dxT[c * DXS + nl];
      const float d1 = dxT[c * DXS + nl + 64];
      const float4* ar = (const float4*)&askc[cc * 144 + e0];
#pragma unroll
      for (int q = 0; q < 9; ++q) {
        const float4 v = ar[q];
        a0[q * 4 + 0] = fmaf(d0, v.x, a0[q * 4 + 0]);
        a0[q * 4 + 1] = fmaf(d0, v.y, a0[q * 4 + 1]);
        a0[q * 4 + 2] = fmaf(d0, v.z, a0[q * 4 + 2]);
        a0[q * 4 + 3] = fmaf(d0, v.w, a0[q * 4 + 3]);
        a1[q * 4 + 0] = fmaf(d1, v.x, a1[q * 4 + 0]);
        a1[q * 4 + 1] = fmaf(d1, v.y, a1[q * 4 + 1]);
        a1[q * 4 + 2] = fmaf(d1, v.z, a1[q * 4 + 2]);
        a1[q * 4 + 3] = fmaf(d1, v.w, a1[q * 4 + 3]);
      }
    }
  }
  __syncthreads();   // build reads done -> smem reusable as park space

  // ---- park acc1 in LDS (own slot, stride 37 -> 2-way = free) ----
  float* park = smem + tid * 37;
#pragma unroll
  for (int j = 0; j < 36; ++j) park[j] = a1[j];

  // ---- expm matrix 0, write E ----
  expm_ps6(acc0, eg);
  const int pA = p0 + nl;
  if (pA < NP_) {
    float* gp = E + ((size_t)b * NP_ + pA) * MSTRIDE + e0;
#pragma unroll
    for (int q = 0; q < 9; ++q)
      *(float4*)(gp + q * 4) = make_float4(a0[q * 4 + 0], a0[q * 4 + 1],
                                           a0[q * 4 + 2], a0[q * 4 + 3]);
  }

  // ---- unpark, expm matrix 1, write E ----
#pragma unroll
  for (int j = 0; j < 36; ++j) a0[j] = park[j];
  expm_ps6(acc0, eg);
  const int pB = p0 + 64 + nl;
  if (pB < NP_) {
    float* gp = E + ((size_t)b * NP_ + pB) * MSTRIDE + e0;
#pragma unroll
    for (int q = 0; q < 9; ++q)
      *(float4*)(gp + q * 4) = make_float4(a0[q * 4 + 0], a0[q * 4 + 1],
                                           a0[q * 4 + 2], a0[q * 4 + 3]);
  }
}

// ------------------------------------------------------------------
// K3: per window t: Z = E(t) * E(t+2) * ... * E(t+12); out = [Z(144), xp[t](64)]
// 64 windows/block; stage 76 E's in LDS; per chain step load B rows to regs
// (9 ds_read_b128) then DPP qmm.
// ------------------------------------------------------------------
__global__ __launch_bounds__(256) void k3_chain(const float* __restrict__ E,
                                                const float* __restrict__ x,
                                                float* __restrict__ out) {
  __shared__ float eb[76][LSTRIDE];
  const int b = blockIdx.y;
  const int t0 = blockIdx.x * 64;
  const float* src = E + ((size_t)b * NP_ + t0) * MSTRIDE;
  for (int i = threadIdx.x; i < 76 * 36; i += 256) {
    int m = i / 36, q = i - m * 36;
    *(float4*)(&eb[m][q * 4]) = *(const float4*)(src + (size_t)m * MSTRIDE + q * 4);
  }
  __syncthreads();

  const int r = threadIdx.x & 3;
  const int tl = threadIdx.x >> 2;  // 0..63, window within block
  const int t = t0 + tl;

  float z[3][12], c[3][12];
#pragma unroll
  for (int i = 0; i < 3; ++i) {
    const float* zp = &eb[tl][(3 * r + i) * 12];
    float4 v0 = *(const float4*)(zp + 0);
    float4 v1 = *(const float4*)(zp + 4);
    float4 v2 = *(const float4*)(zp + 8);
    z[i][0] = v0.x; z[i][1] = v0.y; z[i][2]  = v0.z; z[i][3]  = v0.w;
    z[i][4] = v1.x; z[i][5] = v1.y; z[i][6]  = v1.z; z[i][7]  = v1.w;
    z[i][8] = v2.x; z[i][9] = v2.y; z[i][10] = v2.z; z[i][11] = v2.w;
  }

#define CHAIN_STEP(SRC, DST, J)                                          \
  {                                                                      \
    float bb[3][12];                                                     \
    _Pragma("unroll")                                                    \
    for (int i = 0; i < 3; ++i) {                                        \
      const float* ep = &eb[tl + 2 * (J)][(3 * r + i) * 12];             \
      float4 v0 = *(const float4*)(ep + 0);                              \
      float4 v1 = *(const float4*)(ep + 4);                              \
      float4 v2 = *(const float4*)(ep + 8);                              \
      bb[i][0] = v0.x; bb[i][1] = v0.y; bb[i][2]  = v0.z; bb[i][3]  = v0.w; \
      bb[i][4] = v1.x; bb[i][5] = v1.y; bb[i][6]  = v1.z; bb[i][7]  = v1.w; \
      bb[i][8] = v2.x; bb[i][9] = v2.y; bb[i][10] = v2.z; bb[i][11] = v2.w; \
    }                                                                    \
    qmm(SRC, bb, DST);                                                   \
  }
  CHAIN_STEP(z, c, 1)
  CHAIN_STEP(c, z, 2)
  CHAIN_STEP(z, c, 3)
  CHAIN_STEP(c, z, 4)
  CHAIN_STEP(z, c, 5)
  CHAIN_STEP(c, z, 6)
#undef CHAIN_STEP

  const size_t obase = ((size_t)b * T_ + t) * 208;
#pragma unroll
  for (int i = 0; i < 3; ++i) {
    const int row = 3 * r + i;
    *(float4*)(out + obase + row * 12 + 0) = make_float4(z[i][0], z[i][1], z[i][2],  z[i][3]);
    *(float4*)(out + obase + row * 12 + 4) = make_float4(z[i][4], z[i][5], z[i][6],  z[i][7]);
    *(float4*)(out + obase + row * 12 + 8) = make_float4(z[i][8], z[i][9], z[i][10], z[i][11]);
  }
  const int xi = min(max(t - 7, 0), T_ - 1);
  const float* xr = x + ((size_t)b * T_ + xi) * C_ + 16 * r;
#pragma unroll
  for (int q = 0; q < 4; ++q) {
    *(float4*)(out + obase + 144 + 16 * r + q * 4) = *(const float4*)(xr + q * 4);
  }
}

// ------------------------------------------------------------------
extern "C" void kernel_launch(void* const* d_in, const int* in_sizes, int n_in,
                              void* d_out, int out_size, void* d_ws, size_t ws_size,
                              hipStream_t stream) {
  (void)in_sizes; (void)n_in; (void)out_size;
  const float* x = (const float*)d_in[0];
  const float* A = (const float*)d_in[1];
  float* out = (float*)d_out;
  float* E = (float*)d_ws;

  const size_t need = (size_t)B_ * NP_ * MSTRIDE * sizeof(float);  // ~38 MB
  if (ws_size < need) return;

  const int gx = (NP_ + P2_ - 1) / P2_;  // 17
  k12_build_expm<<<dim3(gx, B_), 256, 0, stream>>>(x, A, E);
  k3_chain<<<dim3(T_ / 64, B_), 256, 0, stream>>>(E, x, out);
}

// Round 10
// 109.809 us; speedup vs baseline: 1.5010x; 1.5010x over previous
//
#include <hip/hip_runtime.h>

#define B_ 32
#define T_ 2048
#define C_ 64
#define NP_ 2060          // unique p positions per batch
#define MSTRIDE 144       // floats per 12x12 matrix in global ws
#define LSTRIDE 148       // padded LDS stride for k3 staging

typedef short short8_t __attribute__((ext_vector_type(8)));   // 8 bf16 (4 VGPR)
typedef float f32x4 __attribute__((ext_vector_type(4)));

// f32 -> bf16 (RNE) bit helpers (avoid header API differences)
__device__ __forceinline__ unsigned short f2bf(float f) {
  unsigned u = __float_as_uint(f);
  return (unsigned short)((u + 0x7FFFu + ((u >> 16) & 1u)) >> 16);
}
__device__ __forceinline__ float bf2f(unsigned short s) {
  return __uint_as_float(((unsigned)s) << 16);
}

// ------------------------------------------------------------------
// K1 (MFMA): M[b][p][e] = sum_c dx[p][c] * ask[c][e], scaled 2^-5.
// GEMM M=64 p's per block (16/wave), N=144 (9 tiles), K=64 (2 ksteps).
// bf16 hi/lo split of both operands -> 3 MFMAs per (tile,kstep).
// ask staged once per block in LDS, pre-split, frag-ready:
//   word idx (((ks*9+tile)*4+koct)*16+col)*4 + j2  (j2 = pair of k's)
//   hi words [0,4608), lo words [4608,9216).
// ------------------------------------------------------------------
__global__ __launch_bounds__(256) void k1_mfma(const float* __restrict__ x,
                                               const float* __restrict__ A,
                                               float* __restrict__ M) {
  __shared__ unsigned int askw[9216];   // 36 KB
  const int b = blockIdx.y;
  const int p0 = blockIdx.x * 64;
  const int tid = threadIdx.x;
  const float sc = 1.0f / 32.0f;

  // ---- stage split ask (once per block; A is L2-resident) ----
  for (int P = tid; P < 4608; P += 256) {
    const int j2 = P & 3;
    const int col = (P >> 2) & 15;
    const int koct = (P >> 6) & 3;
    const int rest = P >> 8;            // 0..17
    const int tile = rest % 9;
    const int ks = rest / 9;
    const int e = tile * 16 + col;      // < 144
    const int h = e / 12, w = e - h * 12;
    const int c0 = ks * 32 + koct * 8 + j2 * 2;
    const float v0 = (A[c0 * 144 + e] - A[c0 * 144 + w * 12 + h]) * sc;
    const float v1 = (A[(c0 + 1) * 144 + e] - A[(c0 + 1) * 144 + w * 12 + h]) * sc;
    const unsigned short h0 = f2bf(v0), h1 = f2bf(v1);
    const unsigned short l0 = f2bf(v0 - bf2f(h0)), l1 = f2bf(v1 - bf2f(h1));
    const int widx = (((ks * 9 + tile) * 4 + koct) * 16 + col) * 4 + j2;
    askw[widx] = ((unsigned)h1 << 16) | h0;
    askw[4608 + widx] = ((unsigned)l1 << 16) | l0;
  }
  __syncthreads();

  // ---- A-frags: dx rows for my wave's 16-p strip, bf16 hi/lo ----
  const int wv = tid >> 6;
  const int lane = tid & 63;
  const int mrow = lane & 15;          // A-operand m index
  const int koct = lane >> 4;          // k-octet
  const int p = p0 + wv * 16 + mrow;
  const int i1 = min(max(p - 7, 0), T_ - 1);
  const int i2 = min(max(p - 5, 0), T_ - 1);
  const float* xb = x + (size_t)b * T_ * C_;

  short8_t ah[2], al[2];
#pragma unroll
  for (int ks = 0; ks < 2; ++ks) {
    const int c0 = ks * 32 + koct * 8;
    const float4 u1a = *(const float4*)(xb + (size_t)i1 * C_ + c0);
    const float4 u1b = *(const float4*)(xb + (size_t)i1 * C_ + c0 + 4);
    const float4 u2a = *(const float4*)(xb + (size_t)i2 * C_ + c0);
    const float4 u2b = *(const float4*)(xb + (size_t)i2 * C_ + c0 + 4);
    float d[8];
    d[0] = u2a.x - u1a.x; d[1] = u2a.y - u1a.y;
    d[2] = u2a.z - u1a.z; d[3] = u2a.w - u1a.w;
    d[4] = u2b.x - u1b.x; d[5] = u2b.y - u1b.y;
    d[6] = u2b.z - u1b.z; d[7] = u2b.w - u1b.w;
#pragma unroll
    for (int j = 0; j < 8; ++j) {
      const unsigned short hs = f2bf(d[j]);
      ah[ks][j] = (short)hs;
      al[ks][j] = (short)f2bf(d[j] - bf2f(hs));
    }
  }

  // ---- 9 output tiles: 6 MFMAs each, store D (row=(lane>>4)*4+reg, col=lane&15) ----
  float* Mb = M + (size_t)b * NP_ * MSTRIDE;
  const int dcol = lane & 15;
  const int pbase = p0 + wv * 16 + (lane >> 4) * 4;
  const char* lds = (const char*)askw;
#pragma unroll
  for (int tile = 0; tile < 9; ++tile) {
    f32x4 acc = {0.f, 0.f, 0.f, 0.f};
#pragma unroll
    for (int ks = 0; ks < 2; ++ks) {
      const int fb = (((ks * 9 + tile) * 4 + koct) * 16 + dcol) * 16;  // byte
      const short8_t bh = *(const short8_t*)(lds + fb);
      const short8_t bl = *(const short8_t*)(lds + 18432 + fb);
      acc = __builtin_amdgcn_mfma_f32_16x16x32_bf16(ah[ks], bh, acc, 0, 0, 0);
      acc = __builtin_amdgcn_mfma_f32_16x16x32_bf16(ah[ks], bl, acc, 0, 0, 0);
      acc = __builtin_amdgcn_mfma_f32_16x16x32_bf16(al[ks], bh, acc, 0, 0, 0);
    }
#pragma unroll
    for (int reg = 0; reg < 4; ++reg) {
      const int pr = pbase + reg;
      if (pr < NP_) Mb[(size_t)pr * MSTRIDE + tile * 16 + dcol] = acc[reg];
    }
  }
}

// ------------------------------------------------------------------
// Quad-lane DPP broadcast + register matmul (unchanged, validated)
// ------------------------------------------------------------------
template <int Q>
__device__ __forceinline__ float qb(float v) {
  return __int_as_float(
      __builtin_amdgcn_mov_dpp(__float_as_int(v), Q * 0x55, 0xf, 0xf, true));
}

template <bool ACC>
__device__ __forceinline__ void qmm_t(const float a[3][12], const float b[3][12],
                                      float c[3][12]) {
  if (!ACC) {
#pragma unroll
    for (int i = 0; i < 3; ++i)
#pragma unroll
      for (int j = 0; j < 12; ++j) c[i][j] = 0.f;
  }
#define QMM_K(OWNER, E)                                                  \
  {                                                                      \
    float bk[12];                                                        \
    _Pragma("unroll")                                                    \
    for (int j = 0; j < 12; ++j) bk[j] = qb<OWNER>(b[E][j]);             \
    _Pragma("unroll")                                                    \
    for (int i = 0; i < 3; ++i) {                                        \
      const float av = a[i][3 * OWNER + E];                              \
      _Pragma("unroll")                                                  \
      for (int j = 0; j < 12; ++j) c[i][j] = fmaf(av, bk[j], c[i][j]);   \
    }                                                                    \
  }
  QMM_K(0, 0) QMM_K(0, 1) QMM_K(0, 2)
  QMM_K(1, 0) QMM_K(1, 1) QMM_K(1, 2)
  QMM_K(2, 0) QMM_K(2, 1) QMM_K(2, 2)
  QMM_K(3, 0) QMM_K(3, 1) QMM_K(3, 2)
#undef QMM_K
}
__device__ __forceinline__ void qmm(const float a[3][12], const float b[3][12],
                                    float c[3][12]) { qmm_t<false>(a, b, c); }
__device__ __forceinline__ void qmma(const float a[3][12], const float b[3][12],
                                     float c[3][12]) { qmm_t<true>(a, b, c); }

// ------------------------------------------------------------------
// K2: in-place E = expm(32*Min). PS-6 Taylor (3 mults) + 5 squarings.
// One quad per matrix, 3 rows/lane, max three 36-float arrays live.
// ------------------------------------------------------------------
__global__ __launch_bounds__(256) void k2_expm(float* __restrict__ M) {
  const int gq = (blockIdx.x * 256 + threadIdx.x) >> 2;
  const int r = threadIdx.x & 3;
  float* gp = M + (size_t)gq * MSTRIDE + 36 * r;

  float a[3][12], t2[3][12], t3[3][12];
#pragma unroll
  for (int i = 0; i < 3; ++i)
#pragma unroll
    for (int q4 = 0; q4 < 3; ++q4) {
      float4 v = *(const float4*)(gp + i * 12 + q4 * 4);
      a[i][q4 * 4 + 0] = v.x;
      a[i][q4 * 4 + 1] = v.y;
      a[i][q4 * 4 + 2] = v.z;
      a[i][q4 * 4 + 3] = v.w;
    }

  qmm(a, a, t2);      // M2
  qmm(t2, a, t3);     // M3
#pragma unroll
  for (int i = 0; i < 3; ++i)
#pragma unroll
    for (int j = 0; j < 12; ++j) {
      const float av = a[i][j], t2v = t2[i][j], t3v = t3[i][j];
      t2[i][j] = av + t2v * 0.5f + t3v * (1.0f / 6.0f) +
                 ((j == 3 * r + i) ? 1.0f : 0.0f);
      a[i][j] = av * (1.0f / 24.0f) + t2v * (1.0f / 120.0f) +
                t3v * (1.0f / 720.0f);
    }
  qmma(t3, a, t2);    // t2 += M3*W

  qmm(t2, t2, t3);
  qmm(t3, t3, t2);
  qmm(t2, t2, t3);
  qmm(t3, t3, t2);
  qmm(t2, t2, t3);    // E in t3

#pragma unroll
  for (int i = 0; i < 3; ++i)
#pragma unroll
    for (int q4 = 0; q4 < 3; ++q4)
      *(float4*)(gp + i * 12 + q4 * 4) =
          make_float4(t3[i][q4 * 4 + 0], t3[i][q4 * 4 + 1],
                      t3[i][q4 * 4 + 2], t3[i][q4 * 4 + 3]);
}

// ------------------------------------------------------------------
// K3: chain of 7 E's per window + passthrough (unchanged, validated)
// ------------------------------------------------------------------
__global__ __launch_bounds__(256) void k3_chain(const float* __restrict__ E,
                                                const float* __restrict__ x,
                                                float* __restrict__ out) {
  __shared__ float eb[76][LSTRIDE];
  const int b = blockIdx.y;
  const int t0 = blockIdx.x * 64;
  const float* src = E + ((size_t)b * NP_ + t0) * MSTRIDE;
  for (int i = threadIdx.x; i < 76 * 36; i += 256) {
    int m = i / 36, q = i - m * 36;
    *(float4*)(&eb[m][q * 4]) = *(const float4*)(src + (size_t)m * MSTRIDE + q * 4);
  }
  __syncthreads();

  const int r = threadIdx.x & 3;
  const int tl = threadIdx.x >> 2;
  const int t = t0 + tl;

  float z[3][12], c[3][12];
#pragma unroll
  for (int i = 0; i < 3; ++i) {
    const float* zp = &eb[tl][(3 * r + i) * 12];
    float4 v0 = *(const float4*)(zp + 0);
    float4 v1 = *(const float4*)(zp + 4);
    float4 v2 = *(const float4*)(zp + 8);
    z[i][0] = v0.x; z[i][1] = v0.y; z[i][2]  = v0.z; z[i][3]  = v0.w;
    z[i][4] = v1.x; z[i][5] = v1.y; z[i][6]  = v1.z; z[i][7]  = v1.w;
    z[i][8] = v2.x; z[i][9] = v2.y; z[i][10] = v2.z; z[i][11] = v2.w;
  }

#define CHAIN_STEP(SRC, DST, J)                                          \
  {                                                                      \
    float bb[3][12];                                                     \
    _Pragma("unroll")                                                    \
    for (int i = 0; i < 3; ++i) {                                        \
      const float* ep = &eb[tl + 2 * (J)][(3 * r + i) * 12];             \
      float4 v0 = *(const float4*)(ep + 0);                              \
      float4 v1 = *(const float4*)(ep + 4);                              \
      float4 v2 = *(const float4*)(ep + 8);                              \
      bb[i][0] = v0.x; bb[i][1] = v0.y; bb[i][2]  = v0.z; bb[i][3]  = v0.w; \
      bb[i][4] = v1.x; bb[i][5] = v1.y; bb[i][6]  = v1.z; bb[i][7]  = v1.w; \
      bb[i][8] = v2.x; bb[i][9] = v2.y; bb[i][10] = v2.z; bb[i][11] = v2.w; \
    }                                                                    \
    qmm(SRC, bb, DST);                                                   \
  }
  CHAIN_STEP(z, c, 1)
  CHAIN_STEP(c, z, 2)
  CHAIN_STEP(z, c, 3)
  CHAIN_STEP(c, z, 4)
  CHAIN_STEP(z, c, 5)
  CHAIN_STEP(c, z, 6)
#undef CHAIN_STEP

  const size_t obase = ((size_t)b * T_ + t) * 208;
#pragma unroll
  for (int i = 0; i < 3; ++i) {
    const int row = 3 * r + i;
    *(float4*)(out + obase + row * 12 + 0) = make_float4(z[i][0], z[i][1], z[i][2],  z[i][3]);
    *(float4*)(out + obase + row * 12 + 4) = make_float4(z[i][4], z[i][5], z[i][6],  z[i][7]);
    *(float4*)(out + obase + row * 12 + 8) = make_float4(z[i][8], z[i][9], z[i][10], z[i][11]);
  }
  const int xi = min(max(t - 7, 0), T_ - 1);
  const float* xr = x + ((size_t)b * T_ + xi) * C_ + 16 * r;
#pragma unroll
  for (int q = 0; q < 4; ++q) {
    *(float4*)(out + obase + 144 + 16 * r + q * 4) = *(const float4*)(xr + q * 4);
  }
}

// ------------------------------------------------------------------
extern "C" void kernel_launch(void* const* d_in, const int* in_sizes, int n_in,
                              void* d_out, int out_size, void* d_ws, size_t ws_size,
                              hipStream_t stream) {
  (void)in_sizes; (void)n_in; (void)out_size;
  const float* x = (const float*)d_in[0];
  const float* A = (const float*)d_in[1];
  float* out = (float*)d_out;
  float* M = (float*)d_ws;

  const size_t need = (size_t)B_ * NP_ * MSTRIDE * sizeof(float);  // ~38 MB
  if (ws_size < need) return;

  k1_mfma<<<dim3(33, B_), 256, 0, stream>>>(x, A, M);
  k2_expm<<<dim3((B_ * NP_ * 4) / 256), 256, 0, stream>>>(M);   // 1030 blocks
  k3_chain<<<dim3(T_ / 64, B_), 256, 0, stream>>>(M, x, out);
}